// Round 7
// baseline (365.691 us; speedup 1.0000x reference)
//
#include <hip/hip_runtime.h>
#include <hip/hip_bf16.h>
#include <math.h>

// Stage 0: cast x, w_qkv, w_out -> bf16
// Stage 1a: 256^2 8-phase bf16 MFMA GEMM (x * Wqk^T) -> q,k bf16 [B,H,S,128]
// Stage 1b: same structure (Wv * x^T) -> vt bf16 [B,H,128,S], sigma baked in
// Stage 2: MFMA flash attention (window=512, double-buffered KV) -> attn bf16
// Stage 3: same GEMM -> d_out fp32
//
// GEMM K-loop (m201-template phase discipline): per tile t (parity p), 4
// phases, each {ds_read this phase's frags; stage 1 half-tile; BAR;
// lgkmcnt(0); setprio(1); 16 MFMA; setprio(0); BAR}.
//   ph0: read A m0-1 + B all (12 reads, lgkmcnt(8) hint); stage Ah0(t+1)
//   ph1: read A m2-3; stage Ah1(t+1)
//   ph2: read A m4-5; stage Bh0(t+2)   (B[p] dead after ph0 -> safe)
//   ph3: read A m6-7; stage Bh1(t+2); vmcnt(4) (tail: vmcnt(0))
// Boundary vmcnt(4) drains carried B(t+1) + A(t+1) (8 oldest of 12), leaving
// B(t+2)'s 4 in flight -> next tile ph0's A and B reads are covered.

#define SEQ   4096
#define BATCH 2
#define EMBED 2048
#define HEADS 16
#define HDIM  128
#define NELEM (BATCH * SEQ * EMBED)  // 16777216
#define SCL2E (0.088388347648318447f * 1.4426950408889634f)  // 1/sqrt(128)*log2(e)

typedef __attribute__((ext_vector_type(8))) short short8;
typedef __attribute__((ext_vector_type(4))) float f32x4;

__device__ __forceinline__ unsigned short f2bf(float f) {
    unsigned int u = __float_as_uint(f);
    u = (u + 0x7fff + ((u >> 16) & 1)) >> 16;  // round-to-nearest-even
    return (unsigned short)u;
}

__device__ __forceinline__ unsigned int cvt_pk_bf16(float a, float b) {
    unsigned int r;
    asm volatile("v_cvt_pk_bf16_f32 %0, %1, %2" : "=v"(r) : "v"(a), "v"(b));
    return r;
}

// ---------------------------------------------------------------------------
__global__ void cast_bf16_kernel(const float* __restrict__ src,
                                 unsigned short* __restrict__ dst, int n8)
{
    const int i = blockIdx.x * blockDim.x + threadIdx.x;
    if (i >= n8) return;
    const float4 v0 = ((const float4*)src)[2 * i];
    const float4 v1 = ((const float4*)src)[2 * i + 1];
    union { unsigned short us[8]; uint4 u4; } o;
    o.us[0] = f2bf(v0.x); o.us[1] = f2bf(v0.y); o.us[2] = f2bf(v0.z); o.us[3] = f2bf(v0.w);
    o.us[4] = f2bf(v1.x); o.us[5] = f2bf(v1.y); o.us[6] = f2bf(v1.z); o.us[7] = f2bf(v1.w);
    ((uint4*)dst)[i] = o.u4;
}

// ---------------------------------------------------------------------------
// 256x256 bf16 NT-GEMM: C[M,N] = A[M,K]*B[N,K]^T, fp32 accum. 512 thr, 8 waves
// (2M x 4N), per-wave 128x64 (acc[8][4]). BK=64, double-buffered 128 KiB LDS.
// MODE 0: C fp32 [M,N];  MODE 1: scatter bf16 q/k [B,H,S,128];
// MODE 2: scatter bf16 vt [B,H,128,S] with sigma permutation.
// ---------------------------------------------------------------------------
template <int MODE>
__global__ __launch_bounds__(512, 2)
void gemm256_kernel(const unsigned short* __restrict__ A,
                    const unsigned short* __restrict__ B,
                    float* __restrict__ C,
                    unsigned short* __restrict__ P0,
                    unsigned short* __restrict__ P1,
                    int M, int N, int K)
{
    // Abuf[p] @ p*32768; Bbuf[p] @ 65536 + p*32768
    __shared__ __align__(16) char lds[131072];

    const int tid  = threadIdx.x;
    const int lane = tid & 63;
    const int w    = tid >> 6;       // 0..7
    const int wm   = w >> 2;         // 0..1
    const int wn   = w & 3;          // 0..3
    const int l16  = lane & 15;
    const int kg   = lane >> 4;

    // m-major XCD chunking (R5-validated): chunk = cpx consecutive bidl =
    // few m-rows sweeping all n -> A-panel L2-resident, W streams via L3.
    const int nwg  = gridDim.x * gridDim.y;
    const int bidl = blockIdx.y * gridDim.x + blockIdx.x;
    const int cpx  = nwg >> 3;
    const int swzb = (bidl & 7) * cpx + (bidl >> 3);
    const int m0   = (swzb / gridDim.x) * 256;
    const int n0   = (swzb % gridDim.x) * 256;

    // staging: per instr u, rows u*64 + w*8 + (lane>>3); source chunk
    // pre-swizzled so LDS[row][ch] = global[row][ch ^ (row&7)].
    const int srow = w * 8 + (lane >> 3);
    const int sch8 = ((lane & 7) ^ (lane >> 3)) * 8;

    auto stage = [&](const unsigned short* X, int rowbase, int t2, int ldsbase) {
#pragma unroll
        for (int u = 0; u < 2; ++u) {
            const unsigned short* g = X + (size_t)(rowbase + u * 64 + srow) * K
                                      + t2 * 64 + sch8;
            unsigned int lb = __builtin_amdgcn_readfirstlane(
                (unsigned int)(uintptr_t)(lds + ldsbase + u * 8192 + w * 1024));
            asm volatile("s_mov_b32 m0, %0\n\t"
                         "global_load_lds_dwordx4 %1, off"
                         :: "s"(lb), "v"(g) : "memory");
        }
    };
    auto rdA = [&](int p, int mf, int ks) -> short8 {
        return *(const short8*)(lds + p * 32768 + (wm * 128 + mf * 16 + l16) * 128
                                + (((ks * 4 + kg) ^ (l16 & 7)) << 4));
    };
    auto rdB = [&](int p, int nf, int ks) -> short8 {
        return *(const short8*)(lds + 65536 + p * 32768
                                + (wn * 64 + nf * 16 + l16) * 128
                                + (((ks * 4 + kg) ^ (l16 & 7)) << 4));
    };

    f32x4 acc[8][4];
#pragma unroll
    for (int i = 0; i < 8; ++i)
#pragma unroll
        for (int j = 0; j < 4; ++j) acc[i][j] = (f32x4)0.f;

    const int NT = K >> 6;

    // prologue: A(0), B(0), B(1); wait all but B(1)'s 4 loads
    stage(A, m0 + 0,   0, 0);
    stage(A, m0 + 128, 0, 16384);
    stage(B, n0 + 0,   0, 65536);
    stage(B, n0 + 128, 0, 65536 + 16384);
    if (NT > 1) {
        stage(B, n0 + 0,   1, 65536 + 32768);
        stage(B, n0 + 128, 1, 65536 + 32768 + 16384);
        asm volatile("s_waitcnt vmcnt(4)" ::: "memory");
    } else {
        asm volatile("s_waitcnt vmcnt(0)" ::: "memory");
    }
    __builtin_amdgcn_s_barrier();

    short8 afr[2][2], bfr[4][2];

#define MFMA_QUAD(Q)                                                            \
    __builtin_amdgcn_s_setprio(1);                                              \
    _Pragma("unroll")                                                           \
    for (int i = 0; i < 2; ++i)                                                 \
        _Pragma("unroll")                                                       \
        for (int nf = 0; nf < 4; ++nf)                                          \
            _Pragma("unroll")                                                   \
            for (int ks = 0; ks < 2; ++ks)                                      \
                acc[2 * (Q) + i][nf] = __builtin_amdgcn_mfma_f32_16x16x32_bf16( \
                    afr[i][ks], bfr[nf][ks], acc[2 * (Q) + i][nf], 0, 0, 0);    \
    __builtin_amdgcn_s_setprio(0);

    for (int t = 0; t < NT; ++t) {
        const int p = t & 1;
        // ---- ph0: read A m0-1 + B all; stage Ah0(t+1) ----
#pragma unroll
        for (int i = 0; i < 2; ++i)
#pragma unroll
            for (int ks = 0; ks < 2; ++ks) afr[i][ks] = rdA(p, i, ks);
#pragma unroll
        for (int nf = 0; nf < 4; ++nf)
#pragma unroll
            for (int ks = 0; ks < 2; ++ks) bfr[nf][ks] = rdB(p, nf, ks);
        if (t + 1 < NT) stage(A, m0 + 0, t + 1, (p ^ 1) * 32768);
        asm volatile("s_waitcnt lgkmcnt(8)" ::: "memory");
        __builtin_amdgcn_s_barrier();
        asm volatile("s_waitcnt lgkmcnt(0)" ::: "memory");
        MFMA_QUAD(0)
        __builtin_amdgcn_s_barrier();
        // ---- ph1: read A m2-3; stage Ah1(t+1) ----
#pragma unroll
        for (int i = 0; i < 2; ++i)
#pragma unroll
            for (int ks = 0; ks < 2; ++ks) afr[i][ks] = rdA(p, 2 + i, ks);
        if (t + 1 < NT) stage(A, m0 + 128, t + 1, (p ^ 1) * 32768 + 16384);
        __builtin_amdgcn_s_barrier();
        asm volatile("s_waitcnt lgkmcnt(0)" ::: "memory");
        MFMA_QUAD(1)
        __builtin_amdgcn_s_barrier();
        // ---- ph2: read A m4-5; stage Bh0(t+2) ----
#pragma unroll
        for (int i = 0; i < 2; ++i)
#pragma unroll
            for (int ks = 0; ks < 2; ++ks) afr[i][ks] = rdA(p, 4 + i, ks);
        if (t + 2 < NT) stage(B, n0 + 0, t + 2, 65536 + p * 32768);
        __builtin_amdgcn_s_barrier();
        asm volatile("s_waitcnt lgkmcnt(0)" ::: "memory");
        MFMA_QUAD(2)
        __builtin_amdgcn_s_barrier();
        // ---- ph3: read A m6-7; stage Bh1(t+2); boundary vmcnt ----
#pragma unroll
        for (int i = 0; i < 2; ++i)
#pragma unroll
            for (int ks = 0; ks < 2; ++ks) afr[i][ks] = rdA(p, 6 + i, ks);
        if (t + 2 < NT) stage(B, n0 + 128, t + 2, 65536 + p * 32768 + 16384);
        if (t >= NT - 2) asm volatile("s_waitcnt vmcnt(0)" ::: "memory");
        else             asm volatile("s_waitcnt vmcnt(4)" ::: "memory");
        __builtin_amdgcn_s_barrier();
        asm volatile("s_waitcnt lgkmcnt(0)" ::: "memory");
        MFMA_QUAD(3)
        __builtin_amdgcn_s_barrier();
    }
#undef MFMA_QUAD

    // epilogue: frag (fi,nf,r) -> row m0+wm*128+fi*16+kg*4+r, col n0+wn*64+nf*16+l16
    if (MODE == 1) {
        const int cb = n0 + wn * 64;          // 64-col wave tile: one head slice
        unsigned short* dst = (cb >> 11) ? P1 : P0;
        const int h  = (cb >> 7) & 15;
        const int db = cb & 127;
#pragma unroll
        for (int fi = 0; fi < 8; ++fi)
#pragma unroll
            for (int r = 0; r < 4; ++r) {
                const int mrow = m0 + wm * 128 + fi * 16 + kg * 4 + r;
                const int b = mrow >> 12, s = mrow & 4095;
                unsigned short* drow = dst + ((size_t)((b << 4) + h) * SEQ + s) * HDIM
                                       + db + l16;
#pragma unroll
                for (int nf = 0; nf < 4; ++nf) drow[nf * 16] = f2bf(acc[fi][nf][r]);
            }
    } else if (MODE == 2) {
#pragma unroll
        for (int fi = 0; fi < 8; ++fi)
#pragma unroll
            for (int r = 0; r < 4; ++r) {
                const int mrow = m0 + wm * 128 + fi * 16 + kg * 4 + r;
                const int h = mrow >> 7, d = mrow & 127;
#pragma unroll
                for (int nf = 0; nf < 4; ++nf) {
                    const int col = n0 + wn * 64 + nf * 16 + l16;
                    const int b = col >> 12, s = col & 4095;
                    const int sl = s & 63;
                    const int c = (sl & 0x23) | ((sl & 0x0C) << 1) | ((sl & 0x10) >> 2);
                    P0[((size_t)((b << 4) + h) * HDIM + d) * SEQ + (s & ~63) + c] =
                        f2bf(acc[fi][nf][r]);
                }
            }
    } else {
#pragma unroll
        for (int fi = 0; fi < 8; ++fi)
#pragma unroll
            for (int r = 0; r < 4; ++r) {
                float* crow = C + (size_t)(m0 + wm * 128 + fi * 16 + kg * 4 + r) * N
                              + n0 + wn * 64 + l16;
#pragma unroll
                for (int nf = 0; nf < 4; ++nf) crow[nf * 16] = acc[fi][nf][r];
            }
    }
}

// ---------------------------------------------------------------------------
// MFMA flash attention, double-buffered KV staging (validated R6). Block =
// 512 thr = 8 waves; 128 queries/block. Per buf: K [64 keys][128 d] @ +0,
// Vt [128 d][64 sigma-keys] @ +16384; bufs @ 0 / 32768. Swapped QK^T;
// P lane-local via sigma.
// ---------------------------------------------------------------------------
__global__ __launch_bounds__(512)
void swa_mfma_kernel(const unsigned short* __restrict__ Qg,
                     const unsigned short* __restrict__ Kg,
                     const unsigned short* __restrict__ Vtg,
                     unsigned short* __restrict__ O /* bf16 [B,S,E] */)
{
    __shared__ __align__(16) char lds[65536];

    const int bid = blockIdx.x;
    const int qt  = bid & 31;
    const int h   = (bid >> 5) & 15;
    const int b   = bid >> 9;
    const int q0  = qt * 128;
    const int tid  = threadIdx.x;
    const int w    = tid >> 6;
    const int lane = tid & 63;
    const int l16  = lane & 15;
    const int kg   = lane >> 4;
    const size_t base = (size_t)((b << 4) + h) * SEQ * HDIM;
    const int gq = q0 + w * 16 + l16;

    short8 qf[4];
#pragma unroll
    for (int kw = 0; kw < 4; ++kw)
        qf[kw] = *(const short8*)(Qg + base + (size_t)gq * HDIM + kw * 32 + kg * 8);

    f32x4 acc_o[8];
#pragma unroll
    for (int db = 0; db < 8; ++db) acc_o[db] = (f32x4)0.f;
    float m = -1e30f, l = 0.f;

    auto stageKV = [&](int kt, int buf) {
        const int gk0 = q0 - 512 + kt * 64;
#pragma unroll
        for (int u = 0; u < 2; ++u) {
            {   // K: row=key (id>>4), 16 chunks/row, swizzle ch^(row&7)
                const int id  = u * 512 + w * 64 + lane;
                const int row = id >> 4, ch = id & 15;
                const char* g = (const char*)(Kg + base + (size_t)(gk0 + row) * HDIM
                                              + ((ch ^ (row & 7)) << 3));
                unsigned int lb = __builtin_amdgcn_readfirstlane(
                    (unsigned int)(uintptr_t)(lds + buf * 32768 + u * 8192 + w * 1024));
                asm volatile("s_mov_b32 m0, %0\n\t"
                             "global_load_lds_dwordx4 %1, off"
                             :: "s"(lb), "v"(g) : "memory");
            }
            {   // Vt: row=d (id>>3), 8 chunks/row, swizzle ch^(d&7)
                const int id  = u * 512 + w * 64 + lane;
                const int d   = id >> 3, ch = id & 7;
                const char* g = (const char*)(Vtg + base + (size_t)d * SEQ + gk0
                                              + ((ch ^ (d & 7)) << 3));
                unsigned int lb = __builtin_amdgcn_readfirstlane(
                    (unsigned int)(uintptr_t)(lds + buf * 32768 + 16384
                                              + u * 8192 + w * 1024));
                asm volatile("s_mov_b32 m0, %0\n\t"
                             "global_load_lds_dwordx4 %1, off"
                             :: "s"(lb), "v"(g) : "memory");
            }
        }
    };

    const int kt_start = (qt < 4) ? (8 - 2 * qt) : 0;
    stageKV(kt_start, 0);
    int cur = 0;

    for (int kt = kt_start; kt < 10; ++kt) {
        asm volatile("s_waitcnt vmcnt(0)" ::: "memory");
        __syncthreads();
        if (kt + 1 < 10) stageKV(kt + 1, cur ^ 1);

        const int gk0 = q0 - 512 + kt * 64;
        const char* ldsb = lds + cur * 32768;
        const int qlo = q0 + w * 16;
        const bool active = (gk0 <= qlo + 15) && (gk0 + 63 >= qlo - 512);
        if (active) {
            f32x4 s4[4];
#pragma unroll
            for (int kb = 0; kb < 4; ++kb) s4[kb] = (f32x4)0.f;
#pragma unroll
            for (int kw = 0; kw < 4; ++kw)
#pragma unroll
                for (int kb = 0; kb < 4; ++kb) {
                    short8 kf = *(const short8*)(ldsb + (kb * 16 + l16) * 256
                                                 + (((kw * 4 + kg) ^ (l16 & 7)) << 4));
                    s4[kb] = __builtin_amdgcn_mfma_f32_16x16x32_bf16(
                        kf, qf[kw], s4[kb], 0, 0, 0);
                }

            const int dq = gq - gk0;
            float p[4][4];
            float tm = -1e30f;
#pragma unroll
            for (int kb = 0; kb < 4; ++kb)
#pragma unroll
                for (int r = 0; r < 4; ++r) {
                    const int koff = kb * 16 + kg * 4 + r;
                    const bool valid = (koff <= dq) && (koff >= dq - 512);
                    const float sv = valid ? s4[kb][r] * SCL2E : -1e30f;
                    p[kb][r] = sv;
                    tm = fmaxf(tm, sv);
                }
            tm = fmaxf(tm, __shfl_xor(tm, 16));
            tm = fmaxf(tm, __shfl_xor(tm, 32));
            const float mn   = fmaxf(m, tm);
            const float corr = __builtin_amdgcn_exp2f(m - mn);
            m = mn;
            l *= corr;
            float cr[4];
#pragma unroll
            for (int r = 0; r < 4; ++r) cr[r] = __shfl(corr, kg * 4 + r);
#pragma unroll
            for (int db = 0; db < 8; ++db)
#pragma unroll
                for (int r = 0; r < 4; ++r) acc_o[db][r] *= cr[r];

            float ts = 0.f;
#pragma unroll
            for (int kb = 0; kb < 4; ++kb)
#pragma unroll
                for (int r = 0; r < 4; ++r) {
                    const float pv = (p[kb][r] > -1e29f)
                                         ? __builtin_amdgcn_exp2f(p[kb][r] - m) : 0.f;
                    p[kb][r] = pv;
                    ts += pv;
                }
            ts += __shfl_xor(ts, 16);
            ts += __shfl_xor(ts, 32);
            l += ts;

            unsigned int dw[4][2];
#pragma unroll
            for (int kb = 0; kb < 4; ++kb) {
                dw[kb][0] = cvt_pk_bf16(p[kb][0], p[kb][1]);
                dw[kb][1] = cvt_pk_bf16(p[kb][2], p[kb][3]);
            }
#pragma unroll
            for (int w2 = 0; w2 < 2; ++w2) {
                union { unsigned int u[4]; short8 v; } pu;
                pu.u[0] = dw[2 * w2][0];     pu.u[1] = dw[2 * w2][1];
                pu.u[2] = dw[2 * w2 + 1][0]; pu.u[3] = dw[2 * w2 + 1][1];
#pragma unroll
                for (int db = 0; db < 8; ++db) {
                    short8 vf = *(const short8*)(ldsb + 16384 + (db * 16 + l16) * 128
                                                 + (((w2 * 4 + kg) ^ (l16 & 7)) << 4));
                    acc_o[db] = __builtin_amdgcn_mfma_f32_16x16x32_bf16(
                        pu.v, vf, acc_o[db], 0, 0, 0);
                }
            }
        }
        cur ^= 1;
    }

    const float inv = 1.0f / l;
    float li[4];
#pragma unroll
    for (int r = 0; r < 4; ++r) li[r] = __shfl(inv, kg * 4 + r);
#pragma unroll
    for (int db = 0; db < 8; ++db)
#pragma unroll
        for (int r = 0; r < 4; ++r) {
            const int gqr = q0 + w * 16 + kg * 4 + r;
            O[((size_t)b * SEQ + gqr) * EMBED + h * HDIM + db * 16 + l16] =
                f2bf(acc_o[db][r] * li[r]);
        }
}

// ---------------------------------------------------------------------------
extern "C" void kernel_launch(void* const* d_in, const int* in_sizes, int n_in,
                              void* d_out, int out_size, void* d_ws, size_t ws_size,
                              hipStream_t stream)
{
    const float* x     = (const float*)d_in[0];
    const float* w_qkv = (const float*)d_in[1];
    const float* w_out = (const float*)d_in[2];
    float* out = (float*)d_out;

    char* ws = (char*)d_ws;
    unsigned short* xb    = (unsigned short*)(ws);
    unsigned short* wqkvb = (unsigned short*)(ws + 33554432);
    unsigned short* woutb = (unsigned short*)(ws + 58720256);
    unsigned short* qb    = (unsigned short*)(ws + 67108864);
    unsigned short* kb    = (unsigned short*)(ws + 100663296);
    unsigned short* vtb   = (unsigned short*)(ws + 134217728);
    unsigned short* attnb = (unsigned short*)(ws + 167772160);

    const int M = BATCH * SEQ;  // 8192
    dim3 blk(256);

    hipLaunchKernelGGL(cast_bf16_kernel, dim3(NELEM / 8 / 256), blk, 0, stream,
                       x, xb, NELEM / 8);
    hipLaunchKernelGGL(cast_bf16_kernel, dim3(3 * EMBED * EMBED / 8 / 256), blk, 0, stream,
                       w_qkv, wqkvb, 3 * EMBED * EMBED / 8);
    hipLaunchKernelGGL(cast_bf16_kernel, dim3(EMBED * EMBED / 8 / 256), blk, 0, stream,
                       w_out, woutb, EMBED * EMBED / 8);

    // Q,K projection: A = x [8192,2048], B = Wqk rows 0..4095 -> grid (16,32)
    hipLaunchKernelGGL((gemm256_kernel<1>), dim3(16, 32), dim3(512), 0, stream,
                       xb, wqkvb, (float*)nullptr, qb, kb, M, 2 * EMBED, EMBED);

    // V^T projection: A = Wv [2048,2048], B = x [8192,2048] -> grid (32,8)
    hipLaunchKernelGGL((gemm256_kernel<2>), dim3(32, 8), dim3(512), 0, stream,
                       wqkvb + (size_t)2 * EMBED * EMBED, xb, (float*)nullptr,
                       vtb, (unsigned short*)nullptr, EMBED, M, EMBED);

    // attention
    hipLaunchKernelGGL(swa_mfma_kernel, dim3(BATCH * HEADS * (SEQ / 128)), dim3(512),
                       0, stream, qb, kb, vtb, attnb);

    // out projection: grid (8,32)
    hipLaunchKernelGGL((gemm256_kernel<0>), dim3(8, 32), dim3(512), 0, stream,
                       attnb, woutb, out, (unsigned short*)nullptr,
                       (unsigned short*)nullptr, M, EMBED, EMBED);
}